// Round 2
// baseline (86.971 us; speedup 1.0000x reference)
//
#include <hip/hip_runtime.h>

#define HH 56
#define WWID 56
#define HWP (HH*WWID)      // 3136
#define BB 8
#define CC 64
#define NPIX (BB*HWP)      // 25088

// full-wave (64-lane) all-reduce sum: 4 DPP adds + ds_swizzle(^16) + shfl_xor(32)
__device__ __forceinline__ float wave_sum(float x) {
  int xi;
  xi = __builtin_amdgcn_update_dpp(0, __float_as_int(x), 0xB1, 0xF, 0xF, true);  // quad_perm [1,0,3,2]  (^1)
  x += __int_as_float(xi);
  xi = __builtin_amdgcn_update_dpp(0, __float_as_int(x), 0x4E, 0xF, 0xF, true);  // quad_perm [2,3,0,1]  (^2)
  x += __int_as_float(xi);
  xi = __builtin_amdgcn_update_dpp(0, __float_as_int(x), 0x141, 0xF, 0xF, true); // row_half_mirror (^7 within 8; groups of 4 already uniform)
  x += __int_as_float(xi);
  xi = __builtin_amdgcn_update_dpp(0, __float_as_int(x), 0x140, 0xF, 0xF, true); // row_mirror (^15 within 16; groups of 8 uniform)
  x += __int_as_float(xi);
  xi = __builtin_amdgcn_ds_swizzle(__float_as_int(x), 0x401F);                   // xor 16
  x += __int_as_float(xi);
  x += __shfl_xor(x, 32, 64);                                                    // xor 32
  return x;
}

// ---------------- prep: transpose w1/w2/w3 to [c][o], fold conv taps ----------------
__global__ __launch_bounds__(256) void prep_kernel(
    const float* __restrict__ w1, const float* __restrict__ w2, const float* __restrict__ w3,
    const float* __restrict__ w_fc, const float* __restrict__ w_dep,
    float* __restrict__ w1T, float* __restrict__ w2T, float* __restrict__ w3T,
    float* __restrict__ tab)
{
  const int t = threadIdx.x;
  for (int idx = t; idx < 64*64; idx += 256) {
    int o = idx & 63, c = idx >> 6;           // idx = c*64 + o
    w1T[idx] = w1[o*64 + c];
    w2T[idx] = w2[o*64 + c];
    w3T[idx] = w3[o*64 + c];
  }
  // tab[(br*9+tap)*64 + d] = sum_o w_dep[d,o,tap] * w_fc[o,br]
  for (int idx = t; idx < 27*64; idx += 256) {
    int d = idx & 63, bt = idx >> 6;
    int br = bt / 9, tap = bt - br*9;
    float s = 0.f;
    #pragma unroll
    for (int oo = 0; oo < 9; ++oo)
      s += w_dep[d*81 + oo*9 + tap] * w_fc[oo*3 + br];
    tab[idx] = s;
  }
}

// ---------------- qkv: 1x1 convs, output layout [pix][64] fp32 ----------------
__global__ __launch_bounds__(256) void qkv_kernel(
    const float* __restrict__ x,
    const float* __restrict__ b1, const float* __restrict__ b2, const float* __restrict__ b3,
    const float* __restrict__ w1T, const float* __restrict__ w2T, const float* __restrict__ w3T,
    float* __restrict__ q, float* __restrict__ k, float* __restrict__ v)
{
  const int o = threadIdx.x & 63;
  const int wv = __builtin_amdgcn_readfirstlane((int)(threadIdx.x >> 6));
  const int pixbase = blockIdx.x * 32 + wv * 8;      // 8 pixels per wave
  const int n   = pixbase / HWP;
  const int hwb = pixbase - n * HWP;

  float accq[8], acck[8], accv[8];
  const float bq = b1[o], bk = b2[o], bv = b3[o];
  #pragma unroll
  for (int p = 0; p < 8; ++p) { accq[p] = bq; acck[p] = bk; accv[p] = bv; }

  const float* xb = x + (size_t)n * CC * HWP + hwb;

  #pragma unroll 4
  for (int c = 0; c < 64; ++c) {
    const float w1f = w1T[c*64 + o];
    const float w2f = w2T[c*64 + o];
    const float w3f = w3T[c*64 + o];
    float4 x0 = *reinterpret_cast<const float4*>(xb + (size_t)c * HWP);
    float4 x1 = *reinterpret_cast<const float4*>(xb + (size_t)c * HWP + 4);
    float xf[8] = {x0.x, x0.y, x0.z, x0.w, x1.x, x1.y, x1.z, x1.w};
    #pragma unroll
    for (int p = 0; p < 8; ++p) {
      accq[p] = fmaf(w1f, xf[p], accq[p]);
      acck[p] = fmaf(w2f, xf[p], acck[p]);
      accv[p] = fmaf(w3f, xf[p], accv[p]);
    }
  }

  #pragma unroll
  for (int p = 0; p < 8; ++p) {
    size_t off = (size_t)(pixbase + p) * 64 + o;
    q[off] = accq[p]; k[off] = acck[p]; v[off] = accv[p];
  }
}

// ---------------- fused attention (5x5 reflect) + folded depthwise conv (3x3 zero-pad) ----------------
__global__ __launch_bounds__(256) void attn_kernel(
    const float* __restrict__ q, const float* __restrict__ k, const float* __restrict__ v,
    const float* __restrict__ wp, const float* __restrict__ tab,
    const float* __restrict__ b_dep, const float* __restrict__ rate1, const float* __restrict__ rate2,
    float* __restrict__ out)
{
  __shared__ float smem[64][4];
  const int lane = threadIdx.x & 63;            // = d
  const int wid  = __builtin_amdgcn_readfirstlane((int)(threadIdx.x >> 6));
  const int pix  = blockIdx.x * 4 + wid;        // 4 consecutive pixels per block (same image: 3136 % 4 == 0)
  const int n  = pix / HWP;
  const int hw = pix - n * HWP;
  const int h  = hw / WWID;
  const int w  = hw - h * WWID;

  const size_t nbase = (size_t)n * HWP * 64;
  const float qd = q[nbase + (size_t)hw * 64 + lane];

  // RPE dots: qw0 = dot(q, wp[:,0]), qw1 = dot(q, wp[:,1])
  const float wpx = wp[lane*2 + 0];
  const float wpy = wp[lane*2 + 1];
  const float qw0 = wave_sum(qd * wpx);
  const float qw1 = wave_sum(qd * wpy);

  // reflected coordinates for the 5x5 window
  int hr[5], wr[5];
  #pragma unroll
  for (int i = 0; i < 5; ++i) {
    int t = h + i - 2; hr[i] = t < 0 ? -t : (t >= HH ? 2*HH - 2 - t : t);
    t = w + i - 2;     wr[i] = t < 0 ? -t : (t >= WWID ? 2*WWID - 2 - t : t);
  }

  const float C = 2.0f / 55.0f;
  float att[25];
  #pragma unroll
  for (int i = 0; i < 5; ++i) {
    const float dlh = (float)(h - hr[i]) * C;
    #pragma unroll
    for (int j = 0; j < 5; ++j) {
      const int nb = hr[i]*WWID + wr[j];
      const float kd = k[nbase + (size_t)nb * 64 + lane];
      const float dot = wave_sum(qd * kd);
      const float dlw = (float)(w - wr[j]) * C;
      att[i*5 + j] = 0.125f * (dot + qw0 * dlw + qw1 * dlh);
    }
  }

  // softmax over 25 (computed redundantly, identically, on all lanes)
  float m = att[0];
  #pragma unroll
  for (int p = 1; p < 25; ++p) m = fmaxf(m, att[p]);
  float s = 0.f;
  #pragma unroll
  for (int p = 0; p < 25; ++p) { att[p] = __expf(att[p] - m); s += att[p]; }
  const float inv = 1.0f / s;

  // weighted V
  float oatt = 0.f;
  #pragma unroll
  for (int i = 0; i < 5; ++i) {
    #pragma unroll
    for (int j = 0; j < 5; ++j) {
      const int nb = hr[i]*WWID + wr[j];
      const float vd = v[nbase + (size_t)nb * 64 + lane];
      oatt = fmaf(att[i*5 + j], vd, oatt);
    }
  }
  oatt *= inv;

  // folded depthwise conv branch (zero padding)
  float cacc = 0.f;
  #pragma unroll
  for (int kh = 0; kh < 3; ++kh) {
    const int hh = h + kh - 1;
    if (hh >= 0 && hh < HH) {
      #pragma unroll
      for (int kw = 0; kw < 3; ++kw) {
        const int wc = w + kw - 1;
        if (wc >= 0 && wc < WWID) {
          const int tap = kh*3 + kw;
          const size_t off = nbase + (size_t)(hh*WWID + wc) * 64 + lane;
          cacc = fmaf(tab[(0*9 + tap)*64 + lane], q[off], cacc);
          cacc = fmaf(tab[(1*9 + tap)*64 + lane], k[off], cacc);
          cacc = fmaf(tab[(2*9 + tap)*64 + lane], v[off], cacc);
        }
      }
    }
  }
  cacc += b_dep[lane];

  const float r1 = rate1[0];
  const float r2 = rate2[0];
  const float res = r1 * oatt + r2 * cacc;

  // stage through LDS so the global store is 16B-coalesced over hw
  smem[lane][wid] = res;
  __syncthreads();
  if (threadIdx.x < 64) {
    const int c = threadIdx.x;
    const int hw0 = (blockIdx.x * 4) % HWP;
    const int n0  = (blockIdx.x * 4) / HWP;
    float4 o4 = *reinterpret_cast<const float4*>(&smem[c][0]);
    *reinterpret_cast<float4*>(out + (size_t)(n0*64 + c) * HWP + hw0) = o4;
  }
}

extern "C" void kernel_launch(void* const* d_in, const int* in_sizes, int n_in,
                              void* d_out, int out_size, void* d_ws, size_t ws_size,
                              hipStream_t stream) {
  const float* x     = (const float*)d_in[0];
  const float* w1    = (const float*)d_in[1];
  const float* b1    = (const float*)d_in[2];
  const float* w2    = (const float*)d_in[3];
  const float* b2    = (const float*)d_in[4];
  const float* w3    = (const float*)d_in[5];
  const float* b3    = (const float*)d_in[6];
  const float* wp    = (const float*)d_in[7];
  // d_in[8] = bp : cancels in the RPE difference, unused
  const float* w_fc  = (const float*)d_in[9];
  const float* w_dep = (const float*)d_in[10];
  const float* b_dep = (const float*)d_in[11];
  const float* rate1 = (const float*)d_in[12];
  const float* rate2 = (const float*)d_in[13];
  float* out = (float*)d_out;

  float* ws = (float*)d_ws;
  float* q   = ws;                       // NPIX*64
  float* k   = ws + (size_t)NPIX*64;
  float* v   = ws + (size_t)2*NPIX*64;
  float* w1T = ws + (size_t)3*NPIX*64;   // 4096
  float* w2T = w1T + 4096;
  float* w3T = w2T + 4096;
  float* tab = w3T + 4096;               // 27*64

  prep_kernel<<<1, 256, 0, stream>>>(w1, w2, w3, w_fc, w_dep, w1T, w2T, w3T, tab);
  qkv_kernel<<<NPIX/32, 256, 0, stream>>>(x, b1, b2, b3, w1T, w2T, w3T, q, k, v);
  attn_kernel<<<NPIX/4, 256, 0, stream>>>(q, k, v, wp, tab, b_dep, rate1, rate2, out);
}

// Round 3
// 59.052 us; speedup vs baseline: 1.4728x; 1.4728x over previous
//
#include <hip/hip_runtime.h>

#define HH 56
#define WWID 56
#define HWP (HH*WWID)      // 3136
#define BB 8
#define CC 64
#define NPIX (BB*HWP)      // 25088

// 16-lane-group all-reduce sum, DPP only (no LDS pipe). All 16 lanes end with the sum.
__device__ __forceinline__ float grp_sum(float x) {
  int xi;
  xi = __builtin_amdgcn_update_dpp(0, __float_as_int(x), 0xB1, 0xF, 0xF, true);  // quad_perm [1,0,3,2]  (^1)
  x += __int_as_float(xi);
  xi = __builtin_amdgcn_update_dpp(0, __float_as_int(x), 0x4E, 0xF, 0xF, true);  // quad_perm [2,3,0,1]  (^2)
  x += __int_as_float(xi);
  xi = __builtin_amdgcn_update_dpp(0, __float_as_int(x), 0x141, 0xF, 0xF, true); // row_half_mirror
  x += __int_as_float(xi);
  xi = __builtin_amdgcn_update_dpp(0, __float_as_int(x), 0x140, 0xF, 0xF, true); // row_mirror
  x += __int_as_float(xi);
  return x;
}

__device__ __forceinline__ float dot4(float4 a, float4 b) {
  float t = a.x * b.x;
  t = fmaf(a.y, b.y, t);
  t = fmaf(a.z, b.z, t);
  t = fmaf(a.w, b.w, t);
  return t;
}

// ---------------- prep: pack w1/w2/w3 to [c/4][o][4], fold conv taps ----------------
__global__ __launch_bounds__(256) void prep_kernel(
    const float* __restrict__ w1, const float* __restrict__ w2, const float* __restrict__ w3,
    const float* __restrict__ w_fc, const float* __restrict__ w_dep,
    float* __restrict__ w1P, float* __restrict__ w2P, float* __restrict__ w3P,
    float* __restrict__ tab)
{
  const int t = threadIdx.x;
  for (int idx = t; idx < 64*64; idx += 256) {
    int c4 = idx >> 8, r = idx & 255, o = r >> 2, e = r & 3;
    int c = c4*4 + e;
    w1P[idx] = w1[o*64 + c];
    w2P[idx] = w2[o*64 + c];
    w3P[idx] = w3[o*64 + c];
  }
  // tab[(br*9+tap)*64 + d] = sum_o w_dep[d,o,tap] * w_fc[o,br]
  for (int idx = t; idx < 27*64; idx += 256) {
    int d = idx & 63, bt = idx >> 6;
    int br = bt / 9, tap = bt - br*9;
    float s = 0.f;
    #pragma unroll
    for (int oo = 0; oo < 9; ++oo)
      s += w_dep[d*81 + oo*9 + tap] * w_fc[oo*3 + br];
    tab[idx] = s;
  }
}

// ---------------- qkv: 1x1 convs, output layout [pix][64] fp32 ----------------
__global__ __launch_bounds__(256) void qkv_kernel(
    const float* __restrict__ x,
    const float* __restrict__ b1, const float* __restrict__ b2, const float* __restrict__ b3,
    const float* __restrict__ w1P, const float* __restrict__ w2P, const float* __restrict__ w3P,
    float* __restrict__ q, float* __restrict__ k, float* __restrict__ v)
{
  const int o = threadIdx.x & 63;
  const int wv = __builtin_amdgcn_readfirstlane((int)(threadIdx.x >> 6));
  const int pixbase = blockIdx.x * 32 + wv * 8;      // 8 pixels per wave
  const int n   = pixbase / HWP;
  const int hwb = pixbase - n * HWP;

  float accq[8], acck[8], accv[8];
  const float bq = b1[o], bk = b2[o], bv = b3[o];
  #pragma unroll
  for (int p = 0; p < 8; ++p) { accq[p] = bq; acck[p] = bk; accv[p] = bv; }

  const float* xb = x + (size_t)n * CC * HWP + hwb;

  #pragma unroll 4
  for (int c4 = 0; c4 < 16; ++c4) {
    const float4 wq = *reinterpret_cast<const float4*>(w1P + c4*256 + o*4);
    const float4 wk = *reinterpret_cast<const float4*>(w2P + c4*256 + o*4);
    const float4 wv4 = *reinterpret_cast<const float4*>(w3P + c4*256 + o*4);
    const float wqa[4] = {wq.x, wq.y, wq.z, wq.w};
    const float wka[4] = {wk.x, wk.y, wk.z, wk.w};
    const float wva[4] = {wv4.x, wv4.y, wv4.z, wv4.w};
    #pragma unroll
    for (int e = 0; e < 4; ++e) {
      const float* xr = xb + (size_t)(c4*4 + e) * HWP;
      float4 x0 = *reinterpret_cast<const float4*>(xr);
      float4 x1 = *reinterpret_cast<const float4*>(xr + 4);
      float xf[8] = {x0.x, x0.y, x0.z, x0.w, x1.x, x1.y, x1.z, x1.w};
      #pragma unroll
      for (int p = 0; p < 8; ++p) {
        accq[p] = fmaf(wqa[e], xf[p], accq[p]);
        acck[p] = fmaf(wka[e], xf[p], acck[p]);
        accv[p] = fmaf(wva[e], xf[p], accv[p]);
      }
    }
  }

  #pragma unroll
  for (int p = 0; p < 8; ++p) {
    size_t off = (size_t)(pixbase + p) * 64 + o;
    q[off] = accq[p]; k[off] = acck[p]; v[off] = accv[p];
  }
}

// ---------------- fused attention (5x5 reflect) + folded depthwise conv (3x3 zero-pad) ----------------
// block = 256 threads = 4 waves = 16 pixels; 16-lane group per pixel, lane holds 4 channels.
__global__ __launch_bounds__(256) void attn_kernel(
    const float* __restrict__ q, const float* __restrict__ k, const float* __restrict__ v,
    const float* __restrict__ wp, const float* __restrict__ tab,
    const float* __restrict__ b_dep, const float* __restrict__ rate1, const float* __restrict__ rate2,
    float* __restrict__ out)
{
  __shared__ float sout[64 * 17];
  const int tid  = threadIdx.x;
  const int lane = tid & 63;
  const int wid  = __builtin_amdgcn_readfirstlane((int)(tid >> 6));
  const int grp  = lane >> 4;          // group within wave (0..3)
  const int sl   = lane & 15;          // sub-lane = d/4

  // XCD-chunked swizzle: 1568 blocks, 196 per image -> each XCD owns one image
  const int nwg = NPIX / 16;           // 1568
  const int cpx = nwg / 8;             // 196
  int bid = (int)blockIdx.x;
  bid = (bid & 7) * cpx + (bid >> 3);

  const int pixbase = bid * 16;
  const int pl  = wid * 4 + grp;       // local pixel 0..15
  const int pix = pixbase + pl;
  const int n   = pix / HWP;           // uniform per block (3136 % 16 == 0)
  const int hw  = pix - n * HWP;
  const int h   = hw / WWID;
  const int w   = hw - h * WWID;

  const size_t nbase = (size_t)n * HWP * 64;
  const float4 q4 = *reinterpret_cast<const float4*>(q + nbase + (size_t)hw * 64 + sl * 4);

  // RPE dots: qw0 = dot(q, wp[:,0]), qw1 = dot(q, wp[:,1]);  wp layout [d][2]
  const float4 wa = *reinterpret_cast<const float4*>(wp + 8 * sl);
  const float4 wb = *reinterpret_cast<const float4*>(wp + 8 * sl + 4);
  const float4 wpx4 = {wa.x, wa.z, wb.x, wb.z};
  const float4 wpy4 = {wa.y, wa.w, wb.y, wb.w};
  const float qw0 = grp_sum(dot4(q4, wpx4));
  const float qw1 = grp_sum(dot4(q4, wpy4));

  // reflected coordinates for the 5x5 window
  int hr[5], wr[5];
  #pragma unroll
  for (int i = 0; i < 5; ++i) {
    int t = h + i - 2; hr[i] = t < 0 ? -t : (t >= HH ? 2*HH - 2 - t : t);
    t = w + i - 2;     wr[i] = t < 0 ? -t : (t >= WWID ? 2*WWID - 2 - t : t);
  }

  const float C = 2.0f / 55.0f;
  float att[25];
  #pragma unroll
  for (int i = 0; i < 5; ++i) {
    const float dlh = (float)(h - hr[i]) * C;
    #pragma unroll
    for (int j = 0; j < 5; ++j) {
      const int nb = hr[i]*WWID + wr[j];
      const float4 k4 = *reinterpret_cast<const float4*>(k + nbase + (size_t)nb * 64 + sl * 4);
      const float dot = grp_sum(dot4(q4, k4));
      const float dlw = (float)(w - wr[j]) * C;
      att[i*5 + j] = 0.125f * (dot + qw0 * dlw + qw1 * dlh);
    }
  }

  // softmax over 25 (redundant across the 16 lanes of the group)
  float m = att[0];
  #pragma unroll
  for (int p = 1; p < 25; ++p) m = fmaxf(m, att[p]);
  float s = 0.f;
  #pragma unroll
  for (int p = 0; p < 25; ++p) { att[p] = __expf(att[p] - m); s += att[p]; }
  const float inv = 1.0f / s;

  // weighted V
  float4 oatt = {0.f, 0.f, 0.f, 0.f};
  #pragma unroll
  for (int i = 0; i < 5; ++i) {
    #pragma unroll
    for (int j = 0; j < 5; ++j) {
      const int nb = hr[i]*WWID + wr[j];
      const float4 v4 = *reinterpret_cast<const float4*>(v + nbase + (size_t)nb * 64 + sl * 4);
      const float a = att[i*5 + j];
      oatt.x = fmaf(a, v4.x, oatt.x);
      oatt.y = fmaf(a, v4.y, oatt.y);
      oatt.z = fmaf(a, v4.z, oatt.z);
      oatt.w = fmaf(a, v4.w, oatt.w);
    }
  }

  // folded depthwise conv branch (zero padding)
  float4 cacc = {0.f, 0.f, 0.f, 0.f};
  #pragma unroll
  for (int kh = 0; kh < 3; ++kh) {
    const int hh = h + kh - 1;
    #pragma unroll
    for (int kw = 0; kw < 3; ++kw) {
      const int wc = w + kw - 1;
      const bool ok = ((unsigned)hh < HH) && ((unsigned)wc < WWID);
      const int nb = ok ? hh*WWID + wc : hw;      // safe address
      const float mk = ok ? 1.0f : 0.0f;
      const int tap = kh*3 + kw;
      const size_t off = nbase + (size_t)nb * 64 + sl * 4;
      const float4 qn = *reinterpret_cast<const float4*>(q + off);
      const float4 kn = *reinterpret_cast<const float4*>(k + off);
      const float4 vn = *reinterpret_cast<const float4*>(v + off);
      const float4 tq = *reinterpret_cast<const float4*>(tab + (0*9 + tap)*64 + sl*4);
      const float4 tk = *reinterpret_cast<const float4*>(tab + (1*9 + tap)*64 + sl*4);
      const float4 tv = *reinterpret_cast<const float4*>(tab + (2*9 + tap)*64 + sl*4);
      float sx = tq.x*qn.x; sx = fmaf(tk.x, kn.x, sx); sx = fmaf(tv.x, vn.x, sx);
      float sy = tq.y*qn.y; sy = fmaf(tk.y, kn.y, sy); sy = fmaf(tv.y, vn.y, sy);
      float sz = tq.z*qn.z; sz = fmaf(tk.z, kn.z, sz); sz = fmaf(tv.z, vn.z, sz);
      float sw = tq.w*qn.w; sw = fmaf(tk.w, kn.w, sw); sw = fmaf(tv.w, vn.w, sw);
      cacc.x = fmaf(mk, sx, cacc.x);
      cacc.y = fmaf(mk, sy, cacc.y);
      cacc.z = fmaf(mk, sz, cacc.z);
      cacc.w = fmaf(mk, sw, cacc.w);
    }
  }
  const float4 bd = *reinterpret_cast<const float4*>(b_dep + sl*4);
  const float r1 = rate1[0];
  const float r2 = rate2[0];

  float res[4];
  res[0] = r1 * (oatt.x * inv) + r2 * (cacc.x + bd.x);
  res[1] = r1 * (oatt.y * inv) + r2 * (cacc.y + bd.y);
  res[2] = r1 * (oatt.z * inv) + r2 * (cacc.z + bd.z);
  res[3] = r1 * (oatt.w * inv) + r2 * (cacc.w + bd.w);

  // stage to LDS [ch][16 px + pad] then write coalesced float4 per thread
  #pragma unroll
  for (int e = 0; e < 4; ++e)
    sout[(4*sl + e)*17 + pl] = res[e];
  __syncthreads();

  const int c  = tid >> 2;
  const int e4 = (tid & 3) * 4;
  const int hw0 = pixbase - n * HWP;
  float4 o4 = {sout[c*17 + e4 + 0], sout[c*17 + e4 + 1],
               sout[c*17 + e4 + 2], sout[c*17 + e4 + 3]};
  *reinterpret_cast<float4*>(out + ((size_t)(n*64 + c))*HWP + hw0 + e4) = o4;
}

extern "C" void kernel_launch(void* const* d_in, const int* in_sizes, int n_in,
                              void* d_out, int out_size, void* d_ws, size_t ws_size,
                              hipStream_t stream) {
  const float* x     = (const float*)d_in[0];
  const float* w1    = (const float*)d_in[1];
  const float* b1    = (const float*)d_in[2];
  const float* w2    = (const float*)d_in[3];
  const float* b2    = (const float*)d_in[4];
  const float* w3    = (const float*)d_in[5];
  const float* b3    = (const float*)d_in[6];
  const float* wp    = (const float*)d_in[7];
  // d_in[8] = bp : cancels in the RPE difference, unused
  const float* w_fc  = (const float*)d_in[9];
  const float* w_dep = (const float*)d_in[10];
  const float* b_dep = (const float*)d_in[11];
  const float* rate1 = (const float*)d_in[12];
  const float* rate2 = (const float*)d_in[13];
  float* out = (float*)d_out;

  float* ws = (float*)d_ws;
  float* q   = ws;                       // NPIX*64
  float* k   = ws + (size_t)NPIX*64;
  float* v   = ws + (size_t)2*NPIX*64;
  float* w1P = ws + (size_t)3*NPIX*64;   // 4096
  float* w2P = w1P + 4096;
  float* w3P = w2P + 4096;
  float* tab = w3P + 4096;               // 27*64

  prep_kernel<<<1, 256, 0, stream>>>(w1, w2, w3, w_fc, w_dep, w1P, w2P, w3P, tab);
  qkv_kernel<<<NPIX/32, 256, 0, stream>>>(x, b1, b2, b3, w1P, w2P, w3P, q, k, v);
  attn_kernel<<<NPIX/16, 256, 0, stream>>>(q, k, v, wp, tab, b_dep, rate1, rate2, out);
}

// Round 4
// 47.723 us; speedup vs baseline: 1.8224x; 1.2374x over previous
//
#include <hip/hip_runtime.h>

#define HH 56
#define WWID 56
#define HWP (HH*WWID)      // 3136
#define BB 8
#define CC 64
#define NPIX (BB*HWP)      // 25088

// 16-lane-group all-reduce sum, DPP only. All 16 lanes end with the sum.
__device__ __forceinline__ float grp_sum(float x) {
  int xi;
  xi = __builtin_amdgcn_update_dpp(0, __float_as_int(x), 0xB1, 0xF, 0xF, true);  // quad_perm [1,0,3,2]
  x += __int_as_float(xi);
  xi = __builtin_amdgcn_update_dpp(0, __float_as_int(x), 0x4E, 0xF, 0xF, true);  // quad_perm [2,3,0,1]
  x += __int_as_float(xi);
  xi = __builtin_amdgcn_update_dpp(0, __float_as_int(x), 0x141, 0xF, 0xF, true); // row_half_mirror
  x += __int_as_float(xi);
  xi = __builtin_amdgcn_update_dpp(0, __float_as_int(x), 0x140, 0xF, 0xF, true); // row_mirror
  x += __int_as_float(xi);
  return x;
}

__device__ __forceinline__ float dot4(float4 a, float4 b) {
  float t = a.x * b.x;
  t = fmaf(a.y, b.y, t);
  t = fmaf(a.z, b.z, t);
  t = fmaf(a.w, b.w, t);
  return t;
}

// ---------------- prep: pack w1/w2/w3 to [c/4][o][4], fold conv taps ----------------
__global__ __launch_bounds__(256) void prep_kernel(
    const float* __restrict__ w1, const float* __restrict__ w2, const float* __restrict__ w3,
    const float* __restrict__ w_fc, const float* __restrict__ w_dep,
    float* __restrict__ w1P, float* __restrict__ w2P, float* __restrict__ w3P,
    float* __restrict__ tab)
{
  const int t = threadIdx.x;
  for (int idx = t; idx < 64*64; idx += 256) {
    int c4 = idx >> 8, r = idx & 255, o = r >> 2, e = r & 3;
    int c = c4*4 + e;
    w1P[idx] = w1[o*64 + c];
    w2P[idx] = w2[o*64 + c];
    w3P[idx] = w3[o*64 + c];
  }
  // tab[(br*9+tap)*64 + d] = sum_o w_dep[d,o,tap] * w_fc[o,br]
  for (int idx = t; idx < 27*64; idx += 256) {
    int d = idx & 63, bt = idx >> 6;
    int br = bt / 9, tap = bt - br*9;
    float s = 0.f;
    #pragma unroll
    for (int oo = 0; oo < 9; ++oo)
      s += w_dep[d*81 + oo*9 + tap] * w_fc[oo*3 + br];
    tab[idx] = s;
  }
}

// ---------------- qkv: 1x1 convs via LDS-staged x tile ----------------
// block = 256 threads = 32 pixels; lane = output channel o, wave g owns 8 pixels.
__global__ __launch_bounds__(256) void qkv_kernel(
    const float* __restrict__ x,
    const float* __restrict__ b1, const float* __restrict__ b2, const float* __restrict__ b3,
    const float* __restrict__ w1P, const float* __restrict__ w2P, const float* __restrict__ w3P,
    float* __restrict__ q, float* __restrict__ k, float* __restrict__ v)
{
  __shared__ float xs[64 * 32];     // 8 KB: x[c][px]
  const int tid = threadIdx.x;

  // XCD-chunked swizzle: 784 blocks, 98 per image -> XCD n produces image n
  int bid = (int)blockIdx.x;
  bid = (bid & 7) * 98 + (bid >> 3);

  const int pix0 = bid * 32;
  const int n    = pix0 / HWP;
  const int hw0  = pix0 - n * HWP;
  const float* xb = x + (size_t)n * CC * HWP + hw0;

  // stage x tile: 2048 floats, 2 x float4 per thread, fully coalesced
  #pragma unroll
  for (int r = 0; r < 2; ++r) {
    int idx = r * 256 + tid;        // 0..511
    int c   = idx >> 3;
    int p4  = (idx & 7) * 4;
    float4 xv = *reinterpret_cast<const float4*>(xb + (size_t)c * HWP + p4);
    *reinterpret_cast<float4*>(&xs[c*32 + p4]) = xv;
  }
  __syncthreads();

  const int o = tid & 63;
  const int g = __builtin_amdgcn_readfirstlane((int)(tid >> 6));   // pixel group 0..3

  float accq[8], acck[8], accv[8];
  const float bq = b1[o], bk = b2[o], bv = b3[o];
  #pragma unroll
  for (int p = 0; p < 8; ++p) { accq[p] = bq; acck[p] = bk; accv[p] = bv; }

  #pragma unroll 2
  for (int c4 = 0; c4 < 16; ++c4) {
    const float4 wq  = *reinterpret_cast<const float4*>(w1P + c4*256 + o*4);
    const float4 wk  = *reinterpret_cast<const float4*>(w2P + c4*256 + o*4);
    const float4 wv4 = *reinterpret_cast<const float4*>(w3P + c4*256 + o*4);
    const float wqa[4] = {wq.x, wq.y, wq.z, wq.w};
    const float wka[4] = {wk.x, wk.y, wk.z, wk.w};
    const float wva[4] = {wv4.x, wv4.y, wv4.z, wv4.w};
    #pragma unroll
    for (int e = 0; e < 4; ++e) {
      const float* xr = &xs[(c4*4 + e)*32 + g*8];
      float4 x0 = *reinterpret_cast<const float4*>(xr);        // uniform -> broadcast
      float4 x1 = *reinterpret_cast<const float4*>(xr + 4);
      float xf[8] = {x0.x, x0.y, x0.z, x0.w, x1.x, x1.y, x1.z, x1.w};
      #pragma unroll
      for (int p = 0; p < 8; ++p) {
        accq[p] = fmaf(wqa[e], xf[p], accq[p]);
        acck[p] = fmaf(wka[e], xf[p], acck[p]);
        accv[p] = fmaf(wva[e], xf[p], accv[p]);
      }
    }
  }

  const int pbase = pix0 + g * 8;
  #pragma unroll
  for (int p = 0; p < 8; ++p) {
    size_t off = (size_t)(pbase + p) * 64 + o;   // lanes o consecutive -> 256B stores
    q[off] = accq[p]; k[off] = acck[p]; v[off] = accv[p];
  }
}

// ---------------- fused attention (5x5 reflect) + folded depthwise conv (3x3 zero-pad) ----------------
// block = 256 threads = 16 pixels; 16-lane group per pixel, lane holds 4 channels.
__global__ __launch_bounds__(256) void attn_kernel(
    const float* __restrict__ q, const float* __restrict__ k, const float* __restrict__ v,
    const float* __restrict__ wp, const float* __restrict__ tab,
    const float* __restrict__ b_dep, const float* __restrict__ rate1, const float* __restrict__ rate2,
    float* __restrict__ out)
{
  __shared__ float stab[27 * 64];
  __shared__ float sbd[64];
  __shared__ float sout[64 * 17];

  const int tid  = threadIdx.x;
  // stage folded taps + bias once per block
  for (int i = tid; i < 27*64; i += 256) stab[i] = tab[i];
  if (tid < 64) sbd[tid] = b_dep[tid];
  __syncthreads();

  const int lane = tid & 63;
  const int wid  = __builtin_amdgcn_readfirstlane((int)(tid >> 6));
  const int grp  = lane >> 4;          // group within wave (0..3)
  const int sl   = lane & 15;          // sub-lane = d/4

  // XCD-chunked swizzle: 1568 blocks, 196 per image -> XCD n consumes image n
  int bid = (int)blockIdx.x;
  bid = (bid & 7) * 196 + (bid >> 3);

  const int pixbase = bid * 16;
  const int pl  = wid * 4 + grp;       // local pixel 0..15
  const int pix = pixbase + pl;
  const int n   = pix / HWP;           // uniform per block
  const int hw  = pix - n * HWP;
  const int h   = hw / WWID;
  const int w   = hw - h * WWID;

  const size_t nbase = (size_t)n * HWP * 64;
  const float4 q4 = *reinterpret_cast<const float4*>(q + nbase + (size_t)hw * 64 + sl * 4);

  // RPE dots: qw0 = dot(q, wp[:,0]), qw1 = dot(q, wp[:,1]);  wp layout [d][2]
  const float4 wa = *reinterpret_cast<const float4*>(wp + 8 * sl);
  const float4 wb = *reinterpret_cast<const float4*>(wp + 8 * sl + 4);
  const float4 wpx4 = {wa.x, wa.z, wb.x, wb.z};
  const float4 wpy4 = {wa.y, wa.w, wb.y, wb.w};
  const float qw0 = grp_sum(dot4(q4, wpx4));
  const float qw1 = grp_sum(dot4(q4, wpy4));

  // reflected coordinates for the 5x5 window
  int hr[5], wr[5];
  #pragma unroll
  for (int i = 0; i < 5; ++i) {
    int t = h + i - 2; hr[i] = t < 0 ? -t : (t >= HH ? 2*HH - 2 - t : t);
    t = w + i - 2;     wr[i] = t < 0 ? -t : (t >= WWID ? 2*WWID - 2 - t : t);
  }

  const float C = 2.0f / 55.0f;
  const float A0 = 0.125f * qw0 * C;   // coeff for (w - wr)
  const float A1 = 0.125f * qw1 * C;   // coeff for (h - hr)

  const float* kb = k + nbase + sl * 4;
  float att[25];
  #pragma unroll
  for (int i = 0; i < 5; ++i) {
    const float* krow = kb + (size_t)(hr[i] * WWID) * 64;
    float4 kk[5];
    #pragma unroll
    for (int j = 0; j < 5; ++j)
      kk[j] = *reinterpret_cast<const float4*>(krow + wr[j] * 64);
    const float rh = A1 * (float)(h - hr[i]);
    #pragma unroll
    for (int j = 0; j < 5; ++j) {
      const float dotv = grp_sum(dot4(q4, kk[j]));
      att[i*5 + j] = 0.125f * dotv + A0 * (float)(w - wr[j]) + rh;
    }
  }

  // softmax over 25 (redundant across the 16 lanes of the group)
  float m = att[0];
  #pragma unroll
  for (int p = 1; p < 25; ++p) m = fmaxf(m, att[p]);
  float s = 0.f;
  #pragma unroll
  for (int p = 0; p < 25; ++p) { att[p] = __expf(att[p] - m); s += att[p]; }
  const float inv = 1.0f / s;

  // weighted V, row-batched loads
  const float* vb = v + nbase + sl * 4;
  float4 oatt = {0.f, 0.f, 0.f, 0.f};
  #pragma unroll
  for (int i = 0; i < 5; ++i) {
    const float* vrow = vb + (size_t)(hr[i] * WWID) * 64;
    float4 vv[5];
    #pragma unroll
    for (int j = 0; j < 5; ++j)
      vv[j] = *reinterpret_cast<const float4*>(vrow + wr[j] * 64);
    #pragma unroll
    for (int j = 0; j < 5; ++j) {
      const float a = att[i*5 + j];
      oatt.x = fmaf(a, vv[j].x, oatt.x);
      oatt.y = fmaf(a, vv[j].y, oatt.y);
      oatt.z = fmaf(a, vv[j].z, oatt.z);
      oatt.w = fmaf(a, vv[j].w, oatt.w);
    }
  }

  // folded depthwise conv branch (zero padding), row-batched loads
  float4 cacc = {0.f, 0.f, 0.f, 0.f};
  #pragma unroll
  for (int kh = 0; kh < 3; ++kh) {
    const int hh = h + kh - 1;
    float4 qn[3], kn[3], vn[3];
    float mk[3];
    #pragma unroll
    for (int kw = 0; kw < 3; ++kw) {
      const int wc = w + kw - 1;
      const bool ok = ((unsigned)hh < HH) && ((unsigned)wc < WWID);
      const int nb = ok ? hh*WWID + wc : hw;      // safe address
      mk[kw] = ok ? 1.0f : 0.0f;
      const size_t off = nbase + (size_t)nb * 64 + sl * 4;
      qn[kw] = *reinterpret_cast<const float4*>(q + off);
      kn[kw] = *reinterpret_cast<const float4*>(k + off);
      vn[kw] = *reinterpret_cast<const float4*>(v + off);
    }
    #pragma unroll
    for (int kw = 0; kw < 3; ++kw) {
      const int tap = kh*3 + kw;
      const float4 tq = *reinterpret_cast<const float4*>(&stab[(0*9 + tap)*64 + sl*4]);
      const float4 tk = *reinterpret_cast<const float4*>(&stab[(1*9 + tap)*64 + sl*4]);
      const float4 tv = *reinterpret_cast<const float4*>(&stab[(2*9 + tap)*64 + sl*4]);
      float sx = tq.x*qn[kw].x; sx = fmaf(tk.x, kn[kw].x, sx); sx = fmaf(tv.x, vn[kw].x, sx);
      float sy = tq.y*qn[kw].y; sy = fmaf(tk.y, kn[kw].y, sy); sy = fmaf(tv.y, vn[kw].y, sy);
      float sz = tq.z*qn[kw].z; sz = fmaf(tk.z, kn[kw].z, sz); sz = fmaf(tv.z, vn[kw].z, sz);
      float sw = tq.w*qn[kw].w; sw = fmaf(tk.w, kn[kw].w, sw); sw = fmaf(tv.w, vn[kw].w, sw);
      cacc.x = fmaf(mk[kw], sx, cacc.x);
      cacc.y = fmaf(mk[kw], sy, cacc.y);
      cacc.z = fmaf(mk[kw], sz, cacc.z);
      cacc.w = fmaf(mk[kw], sw, cacc.w);
    }
  }

  const float bdx = sbd[sl*4+0], bdy = sbd[sl*4+1], bdz = sbd[sl*4+2], bdw = sbd[sl*4+3];
  const float r1 = rate1[0];
  const float r2 = rate2[0];

  float res[4];
  res[0] = r1 * (oatt.x * inv) + r2 * (cacc.x + bdx);
  res[1] = r1 * (oatt.y * inv) + r2 * (cacc.y + bdy);
  res[2] = r1 * (oatt.z * inv) + r2 * (cacc.z + bdz);
  res[3] = r1 * (oatt.w * inv) + r2 * (cacc.w + bdw);

  // stage to LDS [ch][16 px + pad] then write coalesced float4 per thread
  #pragma unroll
  for (int e = 0; e < 4; ++e)
    sout[(4*sl + e)*17 + pl] = res[e];
  __syncthreads();

  const int c  = tid >> 2;
  const int e4 = (tid & 3) * 4;
  const int hw0 = pixbase - n * HWP;
  float4 o4 = {sout[c*17 + e4 + 0], sout[c*17 + e4 + 1],
               sout[c*17 + e4 + 2], sout[c*17 + e4 + 3]};
  *reinterpret_cast<float4*>(out + ((size_t)(n*64 + c))*HWP + hw0 + e4) = o4;
}

extern "C" void kernel_launch(void* const* d_in, const int* in_sizes, int n_in,
                              void* d_out, int out_size, void* d_ws, size_t ws_size,
                              hipStream_t stream) {
  const float* x     = (const float*)d_in[0];
  const float* w1    = (const float*)d_in[1];
  const float* b1    = (const float*)d_in[2];
  const float* w2    = (const float*)d_in[3];
  const float* b2    = (const float*)d_in[4];
  const float* w3    = (const float*)d_in[5];
  const float* b3    = (const float*)d_in[6];
  const float* wp    = (const float*)d_in[7];
  // d_in[8] = bp : cancels in the RPE difference, unused
  const float* w_fc  = (const float*)d_in[9];
  const float* w_dep = (const float*)d_in[10];
  const float* b_dep = (const float*)d_in[11];
  const float* rate1 = (const float*)d_in[12];
  const float* rate2 = (const float*)d_in[13];
  float* out = (float*)d_out;

  float* ws = (float*)d_ws;
  float* q   = ws;                       // NPIX*64
  float* k   = ws + (size_t)NPIX*64;
  float* v   = ws + (size_t)2*NPIX*64;
  float* w1P = ws + (size_t)3*NPIX*64;   // 4096
  float* w2P = w1P + 4096;
  float* w3P = w2P + 4096;
  float* tab = w3P + 4096;               // 27*64

  prep_kernel<<<1, 256, 0, stream>>>(w1, w2, w3, w_fc, w_dep, w1P, w2P, w3P, tab);
  qkv_kernel<<<NPIX/32, 256, 0, stream>>>(x, b1, b2, b3, w1P, w2P, w3P, q, k, v);
  attn_kernel<<<NPIX/16, 256, 0, stream>>>(q, k, v, wp, tab, b_dep, rate1, rate2, out);
}